// Round 1
// baseline (351.076 us; speedup 1.0000x reference)
//
#include <hip/hip_runtime.h>
#include <math.h>

// ---------------- problem constants ----------------
#define GG   16      // stripes
#define KK   4       // latents per stripe
#define NN   64      // batch
#define CC   256     // channels
#define SHH  4       // stripe height
#define WW   44      // width
#define PP   176     // pixels per stripe (SHH*WW)
#define HWSZ 2816    // 64*44 (full image h*w)
#define CHW  720896  // CC*HWSZ  (per-n stride in x)
#define TOPKK 22     // int(176*0.125)

// ---------------- DPP wave64 reductions (VALU pipe, not LDS) ----------------
// row_shr:N = 0x110|N ; ROW_BCAST15 = 0x142 ; ROW_BCAST31 = 0x143
// bound_ctrl=true -> invalid source lanes read 0; masked dest rows return old(=0).
template<int CTRL, int RMASK>
__device__ __forceinline__ float dpp0(float v) {
    return __int_as_float(__builtin_amdgcn_update_dpp(
        0, __float_as_int(v), CTRL, RMASK, 0xF, true));
}

// sum of all 64 lanes; result valid on lane 63 only
__device__ __forceinline__ float wave_sum63(float v) {
    v += dpp0<0x111, 0xF>(v);
    v += dpp0<0x112, 0xF>(v);
    v += dpp0<0x114, 0xF>(v);
    v += dpp0<0x118, 0xF>(v);
    v += dpp0<0x142, 0xA>(v);   // bcast15 into rows 1,3
    v += dpp0<0x143, 0xC>(v);   // bcast31 into rows 2,3
    return v;
}
__device__ __forceinline__ float bcast63(float v) {
    return __int_as_float(__builtin_amdgcn_readlane(__float_as_int(v), 63));
}
__device__ __forceinline__ float wave_sum_all(float v) { return bcast63(wave_sum63(v)); }

// max over 64 lanes, broadcast. REQUIRES v >= 0 on every lane OR true max >= 0
// (zero-fill from bound_ctrl/masking never exceeds a nonnegative true max).
__device__ __forceinline__ float wave_max_nn(float v) {
    v = fmaxf(v, dpp0<0x111, 0xF>(v));
    v = fmaxf(v, dpp0<0x112, 0xF>(v));
    v = fmaxf(v, dpp0<0x114, 0xF>(v));
    v = fmaxf(v, dpp0<0x118, 0xF>(v));
    v = fmaxf(v, dpp0<0x142, 0xA>(v));
    v = fmaxf(v, dpp0<0x143, 0xC>(v));
    return bcast63(v);
}

// ---------------- kernel 1: normalize latent basis ----------------
// lb:  [G][K][C]  ->  lbn: [G][C][K] as float (float4 over k per (g,c))
__global__ __launch_bounds__(64) void norm_basis_kernel(
    const float* __restrict__ lb, float* __restrict__ lbn) {
    const int gk = blockIdx.x;          // g*4+k
    const int lane = threadIdx.x;
    const float* row = lb + (size_t)gk * CC;
    float v0 = row[lane], v1 = row[lane + 64], v2 = row[lane + 128], v3 = row[lane + 192];
    float ss = v0 * v0 + v1 * v1 + v2 * v2 + v3 * v3;
    float tot = wave_sum_all(ss);
    float sc = 1.0f / fmaxf(sqrtf(tot), 1e-12f);
    const int g = gk >> 2, k = gk & 3;
    float* dst = lbn + (size_t)g * CC * 4 + k;
    dst[(size_t)lane * 4]        = v0 * sc;
    dst[(size_t)(lane + 64) * 4]  = v1 * sc;
    dst[(size_t)(lane + 128) * 4] = v2 * sc;
    dst[(size_t)(lane + 192) * 4] = v3 * sc;
}

// ---------------- kernel 2: per-stripe main kernel ----------------
// grid (G, N), block 256 = 4 waves; wave s = stripe row s, lanes 0..43 = columns.
__global__ __launch_bounds__(256) void stripe_kernel(
    const float* __restrict__ x, const float* __restrict__ lbn,
    float* __restrict__ sup_ws, float* __restrict__ pw_ws,
    float* __restrict__ pres_ws, float* __restrict__ tok_out) {
    const int g = blockIdx.x;
    const int n = blockIdx.y;
    const int tid = threadIdx.x;
    const int s = tid >> 6;        // wave id = row
    const int lane = tid & 63;
    const bool al = lane < WW;     // active column

    __shared__ float4 Xq[2][SHH][WW];   // 4-channel quads of raw x
    __shared__ float4 Hq[2][SHH][WW];   // horizontal 3-sums
    __shared__ float4 sup4[PP];         // support per pixel (k in components)
    __shared__ float4 pw4[PP];          // pool_w per pixel
    __shared__ float redA[SHH];         // femax per wave
    __shared__ float redB[SHH];         // active count per wave
    __shared__ float zred[SHH][4];      // per-wave partial Z_k

    const size_t nbase = (size_t)n * CHW + (size_t)g * PP;
    const float* xrow = x + nbase + s * WW + (al ? lane : 0);
    const float4* lbg = (const float4*)lbn + (g << 8);   // [c] -> float4 over k

    float d0 = 0, d1 = 0, d2 = 0, d3 = 0, nrm = 0, fe = 0;

    // ---- phase 1: pooled-feature routing accumulators over all 256 channels ----
    int buf = 0;
    float4 xv, Hv;
    for (int c0 = 0; c0 < CC; c0 += 4, buf ^= 1) {
        if (al) {
            xv.x = xrow[(size_t)(c0 + 0) * HWSZ];
            xv.y = xrow[(size_t)(c0 + 1) * HWSZ];
            xv.z = xrow[(size_t)(c0 + 2) * HWSZ];
            xv.w = xrow[(size_t)(c0 + 3) * HWSZ];
            fe += xv.x * xv.x + xv.y * xv.y + xv.z * xv.z + xv.w * xv.w;
            Xq[buf][s][lane] = xv;
        }
        __syncthreads();
        if (al) {
            float4 L = {0, 0, 0, 0}, R = {0, 0, 0, 0};
            if (lane > 0)      L = Xq[buf][s][lane - 1];
            if (lane < WW - 1) R = Xq[buf][s][lane + 1];
            Hv.x = xv.x + L.x + R.x;
            Hv.y = xv.y + L.y + R.y;
            Hv.z = xv.z + L.z + R.z;
            Hv.w = xv.w + L.w + R.w;
            Hq[buf][s][lane] = Hv;
        }
        __syncthreads();
        if (al) {
            float4 U = {0, 0, 0, 0}, D = {0, 0, 0, 0};
            if (s > 0)       U = Hq[buf][s - 1][lane];
            if (s < SHH - 1) D = Hq[buf][s + 1][lane];
            const float k9 = 1.0f / 9.0f;
            float p0 = (Hv.x + U.x + D.x) * k9;
            float p1 = (Hv.y + U.y + D.y) * k9;
            float p2 = (Hv.z + U.z + D.z) * k9;
            float p3 = (Hv.w + U.w + D.w) * k9;
            nrm += p0 * p0 + p1 * p1 + p2 * p2 + p3 * p3;
            float4 l0 = lbg[c0], l1 = lbg[c0 + 1], l2 = lbg[c0 + 2], l3 = lbg[c0 + 3];
            d0 += p0 * l0.x + p1 * l1.x + p2 * l2.x + p3 * l3.x;
            d1 += p0 * l0.y + p1 * l1.y + p2 * l2.y + p3 * l3.y;
            d2 += p0 * l0.z + p1 * l1.z + p2 * l2.z + p3 * l3.z;
            d3 += p0 * l0.w + p1 * l1.w + p2 * l2.w + p3 * l3.w;
        }
    }

    // ---- gating ----
    fe *= (1.0f / 256.0f);
    float fmw = wave_max_nn(al ? fe : 0.0f);
    if (lane == 0) redA[s] = fmw;
    __syncthreads();
    float femax = fmaxf(fmaxf(redA[0], redA[1]), fmaxf(redA[2], redA[3]));
    float den = fmaxf(femax, 1e-6f);
    bool pa = al && ((fe / den) > 0.05f);
    unsigned long long bl = __ballot((int)pa);
    if (lane == 0) redB[s] = (float)__popcll(bl);
    __syncthreads();
    float cnt = redB[0] + redB[1] + redB[2] + redB[3];
    float actv = pa ? 1.0f : 0.0f;
    if (cnt <= 0.0f) actv = (al && (fe > 0.0f)) ? 1.0f : 0.0f;

    // ---- routing softmax ----
    float inv = 8.0f / fmaxf(sqrtf(nrm), 1e-12f);   // /TEMP folded (1/0.125 = 8)
    float L0 = d0 * inv, L1 = d1 * inv, L2 = d2 * inv, L3 = d3 * inv;
    float mx = fmaxf(fmaxf(L0, L1), fmaxf(L2, L3));
    float e0 = expf(L0 - mx), e1 = expf(L1 - mx), e2 = expf(L2 - mx), e3 = expf(L3 - mx);
    float esum = e0 + e1 + e2 + e3;
    float sc = actv / esum;
    float s0 = e0 * sc, s1 = e1 * sc, s2 = e2 * sc, s3 = e3 * sc;  // support

    // ---- per-k pool normalization ----
    float z0 = wave_sum63(s0), z1 = wave_sum63(s1), z2 = wave_sum63(s2), z3 = wave_sum63(s3);
    if (lane == 63) { zred[s][0] = z0; zred[s][1] = z1; zred[s][2] = z2; zred[s][3] = z3; }
    __syncthreads();
    float Z0 = zred[0][0] + zred[1][0] + zred[2][0] + zred[3][0];
    float Z1 = zred[0][1] + zred[1][1] + zred[2][1] + zred[3][1];
    float Z2 = zred[0][2] + zred[1][2] + zred[2][2] + zred[3][2];
    float Z3 = zred[0][3] + zred[1][3] + zred[2][3] + zred[3][3];
    float q0 = s0 / fmaxf(Z0, 1e-6f);
    float q1 = s1 / fmaxf(Z1, 1e-6f);
    float q2 = s2 / fmaxf(Z2, 1e-6f);
    float q3 = s3 / fmaxf(Z3, 1e-6f);

    if (al) {
        const int p = s * WW + lane;
        float4 sv = make_float4(s0, s1, s2, s3);
        float4 qv = make_float4(q0, q1, q2, q3);
        sup4[p] = sv;
        pw4[p] = qv;
        const size_t wsb = ((size_t)(n * GG + g) * PP + p);
        ((float4*)sup_ws)[wsb] = sv;
        ((float4*)pw_ws)[wsb] = qv;
    }
    __syncthreads();

    // ---- top-22 presence: wave s handles k = s ----
    {
        const float* supf = (const float*)sup4;
        const int k = s;
        float v0 = supf[lane * 4 + k];
        float v1 = supf[(lane + 64) * 4 + k];
        float v2 = (lane < PP - 128) ? supf[(lane + 128) * 4 + k] : -1e30f;
        float tks = 0.0f;
        for (int it = 0; it < TOPKK; ++it) {
            float lm = fmaxf(v0, fmaxf(v1, v2));
            float M = wave_max_nn(lm);           // support >= 0, zero-fill safe
            tks += M;
            unsigned long long mk = __ballot((int)(lm == M));
            int src = __ffsll(mk) - 1;
            if (lane == src) {
                if (v0 == M)      v0 = -1e30f;
                else if (v1 == M) v1 = -1e30f;
                else              v2 = -1e30f;
            }
        }
        if (lane == 0) pres_ws[(size_t)n * 64 + g * KK + k] = tks * (1.0f / (float)TOPKK);
    }

    // ---- phase 2: tokens[k][c] = sum_p pool_w[p][k] * x[c][p] ----
    float4 pwa = pw4[lane];
    float4 pwb = pw4[lane + 64];
    float4 pwc = (lane < PP - 128) ? pw4[lane + 128] : make_float4(0, 0, 0, 0);
    const float* xb2 = x + nbase;
    float* tokg = tok_out + (size_t)n * CC * 64 + g * KK;
    for (int i = 0; i < 64; ++i) {
        const int c = (s << 6) + i;   // wave handles its 64 channels
        const float* xc = xb2 + (size_t)c * HWSZ;
        float a0 = xc[lane];
        float a1 = xc[lane + 64];
        float a2 = (lane < PP - 128) ? xc[lane + 128] : 0.0f;
        float t0 = a0 * pwa.x + a1 * pwb.x + a2 * pwc.x;
        float t1 = a0 * pwa.y + a1 * pwb.y + a2 * pwc.y;
        float t2 = a0 * pwa.z + a1 * pwb.z + a2 * pwc.z;
        float t3 = a0 * pwa.w + a1 * pwb.w + a2 * pwc.w;
        t0 = wave_sum63(t0); t1 = wave_sum63(t1); t2 = wave_sum63(t2); t3 = wave_sum63(t3);
        if (lane == 63) {
            *(float4*)(tokg + (size_t)c * 64) = make_float4(t0, t1, t2, t3);
        }
    }
}

// ---------------- kernel 3: scatter support/pool_w into full-res outputs ----------------
// one float4 (4 consecutive gk = one g) per thread; fully coalesced stores.
__global__ __launch_bounds__(256) void scatter_kernel(
    const float* __restrict__ sup_ws, const float* __restrict__ pw_ws,
    float* __restrict__ outS, float* __restrict__ outP) {
    const int t = blockIdx.x * 256 + threadIdx.x;   // < N*HW*16 = 2,883,584
    const int g = t & 15;
    const int rest = t >> 4;          // n*HW + yx
    const int yx = rest % HWSZ;
    const int n = rest / HWSZ;
    const int y = yx / WW;
    const int xx = yx - y * WW;
    float4 vs = make_float4(0, 0, 0, 0);
    float4 vp = make_float4(0, 0, 0, 0);
    if (g == (y >> 2)) {
        const int p = (y & 3) * WW + xx;
        const size_t base = ((size_t)(n * GG + g) * PP + p);
        vs = ((const float4*)sup_ws)[base];
        vp = ((const float4*)pw_ws)[base];
    }
    ((float4*)outS)[t] = vs;
    ((float4*)outP)[t] = vp;
}

// ---------------- kernel 4: presence normalization ----------------
__global__ __launch_bounds__(64) void presence_kernel(
    const float* __restrict__ pres_ws, float* __restrict__ outp) {
    const int n = blockIdx.x;
    const int lane = threadIdx.x;
    float v = pres_ws[(size_t)n * 64 + lane];
    float tot = wave_sum_all(v);
    outp[(size_t)n * 64 + lane] = v / fmaxf(tot, 1e-6f);
}

// ---------------- launch ----------------
extern "C" void kernel_launch(void* const* d_in, const int* in_sizes, int n_in,
                              void* d_out, int out_size, void* d_ws, size_t ws_size,
                              hipStream_t stream) {
    const float* x = (const float*)d_in[0];        // [64,256,64,44]
    const float* lb = (const float*)d_in[1];       // [16,4,256]
    float* ws = (float*)d_ws;
    // workspace layout (floats): lbn 16384 | sup 720896 | pw 720896 | pres 4096
    float* lbn    = ws;
    float* sup_ws = lbn + 16384;
    float* pw_ws  = sup_ws + 720896;
    float* pres_ws = pw_ws + 720896;

    float* out = (float*)d_out;
    float* tok   = out;                    // [64,256,64]  = 1,048,576
    float* pres  = out + 1048576;          // [64,64]      = 4,096
    float* outS  = out + 1052672;          // [64,2816,64] = 11,534,336
    float* outP  = outS + 11534336;        // [64,2816,64] = 11,534,336

    norm_basis_kernel<<<GG * KK, 64, 0, stream>>>(lb, lbn);
    stripe_kernel<<<dim3(GG, NN), 256, 0, stream>>>(x, lbn, sup_ws, pw_ws, pres_ws, tok);
    scatter_kernel<<<(NN * HWSZ * 16) / 256, 256, 0, stream>>>(sup_ws, pw_ws, outS, outP);
    presence_kernel<<<NN, 64, 0, stream>>>(pres_ws, pres);
}

// Round 2
// 349.098 us; speedup vs baseline: 1.0057x; 1.0057x over previous
//
#include <hip/hip_runtime.h>
#include <math.h>

// ---------------- problem constants ----------------
#define GG   16      // stripes
#define KK   4       // latents per stripe
#define NN   64      // batch
#define CC   256     // channels
#define SHH  4       // stripe height
#define WW   44      // width
#define PP   176     // pixels per stripe (SHH*WW)
#define HWSZ 2816    // 64*44 (full image h*w)
#define CHW  720896  // CC*HWSZ  (per-n stride in x)
#define TOPKK 22     // int(176*0.125)
#define NCHUNK 2     // channel chunks for P1/P3
#define CPC  128     // channels per chunk

// ---------------- DPP wave64 reductions (VALU pipe, not LDS) ----------------
template<int CTRL, int RMASK>
__device__ __forceinline__ float dpp0(float v) {
    return __int_as_float(__builtin_amdgcn_update_dpp(
        0, __float_as_int(v), CTRL, RMASK, 0xF, true));
}

// sum of all 64 lanes; result valid on lane 63 only
__device__ __forceinline__ float wave_sum63(float v) {
    v += dpp0<0x111, 0xF>(v);
    v += dpp0<0x112, 0xF>(v);
    v += dpp0<0x114, 0xF>(v);
    v += dpp0<0x118, 0xF>(v);
    v += dpp0<0x142, 0xA>(v);   // bcast15 into rows 1,3
    v += dpp0<0x143, 0xC>(v);   // bcast31 into rows 2,3
    return v;
}
__device__ __forceinline__ float bcast63(float v) {
    return __int_as_float(__builtin_amdgcn_readlane(__float_as_int(v), 63));
}
__device__ __forceinline__ float wave_sum_all(float v) { return bcast63(wave_sum63(v)); }

// max over 64 lanes, broadcast; requires true max >= 0 (zero-fill safe)
__device__ __forceinline__ float wave_max_nn(float v) {
    v = fmaxf(v, dpp0<0x111, 0xF>(v));
    v = fmaxf(v, dpp0<0x112, 0xF>(v));
    v = fmaxf(v, dpp0<0x114, 0xF>(v));
    v = fmaxf(v, dpp0<0x118, 0xF>(v));
    v = fmaxf(v, dpp0<0x142, 0xA>(v));
    v = fmaxf(v, dpp0<0x143, 0xC>(v));
    return bcast63(v);
}

// ---------------- kernel 1: normalize latent basis ----------------
// lb: [G][K][C] -> lbn: [G][C][K] (float4 over k per (g,c))
__global__ __launch_bounds__(64) void norm_basis_kernel(
    const float* __restrict__ lb, float* __restrict__ lbn) {
    const int gk = blockIdx.x;
    const int lane = threadIdx.x;
    const float* row = lb + (size_t)gk * CC;
    float v0 = row[lane], v1 = row[lane + 64], v2 = row[lane + 128], v3 = row[lane + 192];
    float ss = v0 * v0 + v1 * v1 + v2 * v2 + v3 * v3;
    float tot = wave_sum_all(ss);
    float sc = 1.0f / fmaxf(sqrtf(tot), 1e-12f);
    const int g = gk >> 2, k = gk & 3;
    float* dst = lbn + (size_t)g * CC * 4 + k;
    dst[(size_t)lane * 4]         = v0 * sc;
    dst[(size_t)(lane + 64) * 4]  = v1 * sc;
    dst[(size_t)(lane + 128) * 4] = v2 * sc;
    dst[(size_t)(lane + 192) * 4] = v3 * sc;
}

// ---------------- kernel P1: per-(stripe, channel-chunk) partial routing stats ----
// grid (GG*NCHUNK, NN), block 256 (4 waves = 4 rows, lanes 0..43 = cols)
__global__ __launch_bounds__(256) void part_kernel(
    const float* __restrict__ x, const float* __restrict__ lbn,
    float4* __restrict__ dpart, float2* __restrict__ nfpart) {
    const int g = blockIdx.x & 15;
    const int chunk = blockIdx.x >> 4;
    const int n = blockIdx.y;
    const int tid = threadIdx.x;
    const int s = tid >> 6;
    const int lane = tid & 63;
    const bool al = lane < WW;

    __shared__ float4 Xq[2][SHH][WW];
    __shared__ float4 Hq[2][SHH][WW];

    const size_t nbase = (size_t)n * CHW + (size_t)g * PP;
    const float* xrow = x + nbase + s * WW + (al ? lane : 0);
    const float4* lbg = (const float4*)lbn + (g << 8);
    const int cbase = chunk * CPC;

    float d0 = 0, d1 = 0, d2 = 0, d3 = 0, nrm = 0, fe = 0;

    int buf = 0;
    float4 xv, Hv;
    for (int c0 = cbase; c0 < cbase + CPC; c0 += 4, buf ^= 1) {
        if (al) {
            xv.x = xrow[(size_t)(c0 + 0) * HWSZ];
            xv.y = xrow[(size_t)(c0 + 1) * HWSZ];
            xv.z = xrow[(size_t)(c0 + 2) * HWSZ];
            xv.w = xrow[(size_t)(c0 + 3) * HWSZ];
            fe += xv.x * xv.x + xv.y * xv.y + xv.z * xv.z + xv.w * xv.w;
            Xq[buf][s][lane] = xv;
        }
        __syncthreads();
        if (al) {
            float4 L = {0, 0, 0, 0}, R = {0, 0, 0, 0};
            if (lane > 0)      L = Xq[buf][s][lane - 1];
            if (lane < WW - 1) R = Xq[buf][s][lane + 1];
            Hv.x = xv.x + L.x + R.x;
            Hv.y = xv.y + L.y + R.y;
            Hv.z = xv.z + L.z + R.z;
            Hv.w = xv.w + L.w + R.w;
            Hq[buf][s][lane] = Hv;
        }
        __syncthreads();
        if (al) {
            float4 U = {0, 0, 0, 0}, D = {0, 0, 0, 0};
            if (s > 0)       U = Hq[buf][s - 1][lane];
            if (s < SHH - 1) D = Hq[buf][s + 1][lane];
            const float k9 = 1.0f / 9.0f;
            float p0 = (Hv.x + U.x + D.x) * k9;
            float p1 = (Hv.y + U.y + D.y) * k9;
            float p2 = (Hv.z + U.z + D.z) * k9;
            float p3 = (Hv.w + U.w + D.w) * k9;
            nrm += p0 * p0 + p1 * p1 + p2 * p2 + p3 * p3;
            float4 l0 = lbg[c0], l1 = lbg[c0 + 1], l2 = lbg[c0 + 2], l3 = lbg[c0 + 3];
            d0 += p0 * l0.x + p1 * l1.x + p2 * l2.x + p3 * l3.x;
            d1 += p0 * l0.y + p1 * l1.y + p2 * l2.y + p3 * l3.y;
            d2 += p0 * l0.z + p1 * l1.z + p2 * l2.z + p3 * l3.z;
            d3 += p0 * l0.w + p1 * l1.w + p2 * l2.w + p3 * l3.w;
        }
    }
    if (al) {
        const size_t idx = (((size_t)(n * GG + g) * NCHUNK) + chunk) * PP + s * WW + lane;
        dpart[idx] = make_float4(d0, d1, d2, d3);
        nfpart[idx] = make_float2(nrm, fe);
    }
}

// ---------------- kernel P2: finalize routing per stripe ----------------
// grid (GG, NN), block 256
__global__ __launch_bounds__(256) void finalize_kernel(
    const float4* __restrict__ dpart, const float2* __restrict__ nfpart,
    float* __restrict__ sup_ws, float* __restrict__ pw_ws,
    float* __restrict__ pres_ws) {
    const int g = blockIdx.x;
    const int n = blockIdx.y;
    const int tid = threadIdx.x;
    const int s = tid >> 6;
    const int lane = tid & 63;
    const bool al = lane < WW;

    __shared__ float4 sup4[PP];
    __shared__ float redA[SHH];
    __shared__ float redB[SHH];
    __shared__ float zred[SHH][4];

    float d0 = 0, d1 = 0, d2 = 0, d3 = 0, nrm = 0, fe = 0;
    if (al) {
        const int p = s * WW + lane;
        const size_t b = (size_t)(n * GG + g) * NCHUNK * PP + p;
        for (int ch = 0; ch < NCHUNK; ++ch) {
            float4 dv = dpart[b + ch * PP];
            float2 nf = nfpart[b + ch * PP];
            d0 += dv.x; d1 += dv.y; d2 += dv.z; d3 += dv.w;
            nrm += nf.x; fe += nf.y;
        }
    }

    // ---- gating ----
    fe *= (1.0f / 256.0f);
    float fmw = wave_max_nn(al ? fe : 0.0f);
    if (lane == 0) redA[s] = fmw;
    __syncthreads();
    float femax = fmaxf(fmaxf(redA[0], redA[1]), fmaxf(redA[2], redA[3]));
    float den = fmaxf(femax, 1e-6f);
    bool pa = al && ((fe / den) > 0.05f);
    unsigned long long bl = __ballot((int)pa);
    if (lane == 0) redB[s] = (float)__popcll(bl);
    __syncthreads();
    float cnt = redB[0] + redB[1] + redB[2] + redB[3];
    float actv = pa ? 1.0f : 0.0f;
    if (cnt <= 0.0f) actv = (al && (fe > 0.0f)) ? 1.0f : 0.0f;

    // ---- routing softmax ----
    float inv = 8.0f / fmaxf(sqrtf(nrm), 1e-12f);
    float L0 = d0 * inv, L1 = d1 * inv, L2 = d2 * inv, L3 = d3 * inv;
    float mx = fmaxf(fmaxf(L0, L1), fmaxf(L2, L3));
    float e0 = expf(L0 - mx), e1 = expf(L1 - mx), e2 = expf(L2 - mx), e3 = expf(L3 - mx);
    float esum = e0 + e1 + e2 + e3;
    float sc = actv / esum;
    float s0 = e0 * sc, s1 = e1 * sc, s2 = e2 * sc, s3 = e3 * sc;

    // ---- per-k pool normalization ----
    float z0 = wave_sum63(s0), z1 = wave_sum63(s1), z2 = wave_sum63(s2), z3 = wave_sum63(s3);
    if (lane == 63) { zred[s][0] = z0; zred[s][1] = z1; zred[s][2] = z2; zred[s][3] = z3; }
    __syncthreads();
    float Z0 = zred[0][0] + zred[1][0] + zred[2][0] + zred[3][0];
    float Z1 = zred[0][1] + zred[1][1] + zred[2][1] + zred[3][1];
    float Z2 = zred[0][2] + zred[1][2] + zred[2][2] + zred[3][2];
    float Z3 = zred[0][3] + zred[1][3] + zred[2][3] + zred[3][3];
    float q0 = s0 / fmaxf(Z0, 1e-6f);
    float q1 = s1 / fmaxf(Z1, 1e-6f);
    float q2 = s2 / fmaxf(Z2, 1e-6f);
    float q3 = s3 / fmaxf(Z3, 1e-6f);

    if (al) {
        const int p = s * WW + lane;
        float4 sv = make_float4(s0, s1, s2, s3);
        float4 qv = make_float4(q0, q1, q2, q3);
        sup4[p] = sv;
        const size_t wsb = ((size_t)(n * GG + g) * PP + p);
        ((float4*)sup_ws)[wsb] = sv;
        ((float4*)pw_ws)[wsb] = qv;
    }
    __syncthreads();

    // ---- top-22 presence: wave s handles k = s ----
    {
        const float* supf = (const float*)sup4;
        const int k = s;
        float v0 = supf[lane * 4 + k];
        float v1 = supf[(lane + 64) * 4 + k];
        float v2 = (lane < PP - 128) ? supf[(lane + 128) * 4 + k] : -1e30f;
        float tks = 0.0f;
        for (int it = 0; it < TOPKK; ++it) {
            float lm = fmaxf(v0, fmaxf(v1, v2));
            float M = wave_max_nn(lm);
            tks += M;
            unsigned long long mk = __ballot((int)(lm == M));
            int src = __ffsll(mk) - 1;
            if (lane == src) {
                if (v0 == M)      v0 = -1e30f;
                else if (v1 == M) v1 = -1e30f;
                else              v2 = -1e30f;
            }
        }
        if (lane == 0) pres_ws[(size_t)n * 64 + g * KK + k] = tks * (1.0f / (float)TOPKK);
    }
}

// ---------------- kernel P3: tokens ----------------
// grid (GG*NCHUNK, NN), block 256; each wave handles CPC/4=32 channels
__global__ __launch_bounds__(256) void token_kernel(
    const float* __restrict__ x, const float* __restrict__ pw_ws,
    float* __restrict__ tok_out) {
    const int g = blockIdx.x & 15;
    const int chunk = blockIdx.x >> 4;
    const int n = blockIdx.y;
    const int tid = threadIdx.x;
    const int s = tid >> 6;
    const int lane = tid & 63;

    const float4* pwq = (const float4*)pw_ws + (size_t)(n * GG + g) * PP;
    float4 pwa = pwq[lane];
    float4 pwb = pwq[lane + 64];
    float4 pwc = (lane < PP - 128) ? pwq[lane + 128] : make_float4(0, 0, 0, 0);

    const float* xb = x + (size_t)n * CHW + (size_t)g * PP;
    float* tokg = tok_out + (size_t)n * CC * 64 + g * KK;
    const int cb = chunk * CPC + s * (CPC / 4);
    for (int i = 0; i < CPC / 4; ++i) {
        const int c = cb + i;
        const float* xc = xb + (size_t)c * HWSZ;
        float a0 = xc[lane];
        float a1 = xc[lane + 64];
        float a2 = (lane < PP - 128) ? xc[lane + 128] : 0.0f;
        float t0 = a0 * pwa.x + a1 * pwb.x + a2 * pwc.x;
        float t1 = a0 * pwa.y + a1 * pwb.y + a2 * pwc.y;
        float t2 = a0 * pwa.z + a1 * pwb.z + a2 * pwc.z;
        float t3 = a0 * pwa.w + a1 * pwb.w + a2 * pwc.w;
        t0 = wave_sum63(t0); t1 = wave_sum63(t1); t2 = wave_sum63(t2); t3 = wave_sum63(t3);
        if (lane == 63) {
            *(float4*)(tokg + (size_t)c * 64) = make_float4(t0, t1, t2, t3);
        }
    }
}

// ---------------- kernel: scatter with LDS-staged coalesced loads ----------------
// grid (HWSZ/16, NN), block 256: 16 pixels x 16 quad-channels
__global__ __launch_bounds__(256) void scatter_kernel(
    const float4* __restrict__ sup_ws4, const float4* __restrict__ pw_ws4,
    float4* __restrict__ outS, float4* __restrict__ outP) {
    const int n = blockIdx.y;
    const int pix0 = blockIdx.x * 16;
    const int t = threadIdx.x;
    __shared__ float4 qs[16];
    __shared__ float4 qp[16];
    if (t < 32) {
        const int px = t & 15;
        const int pixel = pix0 + px;
        const int y = pixel / WW;
        const int xx = pixel - y * WW;
        const int g = y >> 2;
        const int p = (y & 3) * WW + xx;
        const size_t base = (size_t)(n * GG + g) * PP + p;
        if (t < 16) qs[px] = sup_ws4[base];
        else        qp[px] = pw_ws4[base];
    }
    __syncthreads();
    const int px = t >> 4;
    const int q = t & 15;
    const int pixel = pix0 + px;
    const int g = (pixel / WW) >> 2;
    const float4 z = make_float4(0, 0, 0, 0);
    const size_t o = ((size_t)n * HWSZ + pixel) * 16 + q;
    outS[o] = (q == g) ? qs[px] : z;
    outP[o] = (q == g) ? qp[px] : z;
}

// ---------------- kernel: presence normalization ----------------
__global__ __launch_bounds__(64) void presence_kernel(
    const float* __restrict__ pres_ws, float* __restrict__ outp) {
    const int n = blockIdx.x;
    const int lane = threadIdx.x;
    float v = pres_ws[(size_t)n * 64 + lane];
    float tot = wave_sum_all(v);
    outp[(size_t)n * 64 + lane] = v / fmaxf(tot, 1e-6f);
}

// ---------------- launch ----------------
extern "C" void kernel_launch(void* const* d_in, const int* in_sizes, int n_in,
                              void* d_out, int out_size, void* d_ws, size_t ws_size,
                              hipStream_t stream) {
    const float* x = (const float*)d_in[0];        // [64,256,64,44]
    const float* lb = (const float*)d_in[1];       // [16,4,256]
    float* ws = (float*)d_ws;
    // workspace (floats): lbn 16384 | sup 720896 | pw 720896 | pres 4096  (~5.9 MB)
    float* lbn     = ws;
    float* sup_ws  = lbn + 16384;
    float* pw_ws   = sup_ws + 720896;
    float* pres_ws = pw_ws + 720896;

    float* out = (float*)d_out;
    float* tok  = out;                     // [64,256,64]
    float* pres = out + 1048576;           // [64,64]
    float* outS = out + 1052672;           // [64,2816,64]
    float* outP = outS + 11534336;         // [64,2816,64]

    // P1 partials stashed in the outP region (overwritten by scatter later):
    // dpart: 1024*2*176 float4 = 1,441,792 floats; nfpart: 720,896 floats
    float4* dpart  = (float4*)outP;
    float2* nfpart = (float2*)(outP + 1441792 * 4 / 1);  // after dpart floats
    // note: dpart occupies 1,441,792*4 = 5,767,168 floats; place nfpart after it
    nfpart = (float2*)(outP + 5767168);

    norm_basis_kernel<<<GG * KK, 64, 0, stream>>>(lb, lbn);
    part_kernel<<<dim3(GG * NCHUNK, NN), 256, 0, stream>>>(x, lbn, dpart, nfpart);
    finalize_kernel<<<dim3(GG, NN), 256, 0, stream>>>(dpart, nfpart, sup_ws, pw_ws, pres_ws);
    token_kernel<<<dim3(GG * NCHUNK, NN), 256, 0, stream>>>(x, pw_ws, tok);
    scatter_kernel<<<dim3(HWSZ / 16, NN), 256, 0, stream>>>(
        (const float4*)sup_ws, (const float4*)pw_ws, (float4*)outS, (float4*)outP);
    presence_kernel<<<NN, 64, 0, stream>>>(pres_ws, pres);
}